// Round 7
// baseline (139.606 us; speedup 1.0000x reference)
//
#include <hip/hip_runtime.h>
#include <math.h>

static __device__ __forceinline__ float frcp(float x){ return __builtin_amdgcn_rcpf(x); }
static __device__ __forceinline__ float fsq (float x){ return __builtin_amdgcn_sqrtf(x); }

// ---- DPP row-of-16 reductions; result valid in slot 15 of each row ----
template<int CTRL>
static __device__ __forceinline__ float dppadd(float x){
  int t = __builtin_amdgcn_update_dpp(0, __float_as_int(x), CTRL, 0xf, 0xf, true);
  return x + __int_as_float(t);
}
template<int CTRL>
static __device__ __forceinline__ float dppmax(float x){
  int t = __builtin_amdgcn_update_dpp(__float_as_int(x), __float_as_int(x), CTRL, 0xf, 0xf, false);
  return fmaxf(x, __int_as_float(t));
}
template<int CTRL>
static __device__ __forceinline__ float dppmin(float x){
  int t = __builtin_amdgcn_update_dpp(__float_as_int(x), __float_as_int(x), CTRL, 0xf, 0xf, false);
  return fminf(x, __int_as_float(t));
}
static __device__ __forceinline__ float rsum16s(float x){   // slot-15 valid
  x = dppadd<0x111>(x); x = dppadd<0x112>(x);
  x = dppadd<0x114>(x); x = dppadd<0x118>(x);
  return x;
}
static __device__ __forceinline__ float rmax16s(float x){
  x = dppmax<0x111>(x); x = dppmax<0x112>(x);
  x = dppmax<0x114>(x); x = dppmax<0x118>(x);
  return x;
}
static __device__ __forceinline__ float rmin16s(float x){
  x = dppmin<0x111>(x); x = dppmin<0x112>(x);
  x = dppmin<0x114>(x); x = dppmin<0x118>(x);
  return x;
}
// full row-broadcast sum (for LayerNorm only)
static __device__ __forceinline__ float rsum16b(float x){
  return __int_as_float(__builtin_amdgcn_ds_swizzle(__float_as_int(rsum16s(x)), 0x1F0));
}

__global__ void transpose_w(const float* __restrict__ W, float* __restrict__ Wt){
  int idx = blockIdx.x * 256 + threadIdx.x;
  if (idx < 60 * 48) { int f = idx / 48, j = idx - f * 48; Wt[j * 60 + f] = W[idx]; }
}

#define WOFF 2880   // Wt size in dwords (48*60)
#define FSTR 72     // feat-buffer stride per trajectory (dwords; 72*4 B, bank-staggered)

template<bool USEWT>
__global__ __launch_bounds__(256, 4)
void traj_kernel(const float* __restrict__ coords,
                 const int* __restrict__ lengths,
                 const float* __restrict__ Wsrc,   // Wt [48][60] if USEWT else W [60][48]
                 const float* __restrict__ bias,
                 const float* __restrict__ lnw,
                 const float* __restrict__ lnb,
                 float* __restrict__ out, int B)
{
  __shared__ __align__(16) float lds[WOFF + 16 * FSTR];   // 16128 B

  const int tid  = threadIdx.x;
  const int lane = tid & 63;
  const int s    = lane & 15;
  const int T    = ((tid >> 6) << 2) | (lane >> 4);  // trajectory in block, 0..15
  const int grp  = blockIdx.x * 16 + T;
  const bool bvalid = (grp < B);
  const int b = bvalid ? grp : (B - 1);

  // ---- stage Wt [48][60] into LDS (cooperative) ----
  if (USEWT) {
    for (int idx = tid; idx < 720; idx += 256)
      reinterpret_cast<float4*>(lds)[idx] = reinterpret_cast<const float4*>(Wsrc)[idx];
  } else {
    for (int idx = tid; idx < 2880; idx += 256) {
      int j = idx / 60, f = idx - j * 60;
      lds[idx] = Wsrc[f * 48 + j];
    }
  }
  __syncthreads();

  const int n = lengths[b];      // row-uniform, 4..48
  const int m = n - 1;
  const int half = m >> 1;
  const float* cp = coords + (size_t)b * 480;

  // ---- writer lane: total displacement ||row_{n-1} - row_0|| (early-issued) ----
  float total_disp = 0.f;        // valid on s==15 only
  if (s == 15) {
    const float2* p0 = reinterpret_cast<const float2*>(cp);
    const float2* pl = reinterpret_cast<const float2*>(cp + (size_t)(n - 1) * 10);
    float t = 0.f;
#pragma unroll
    for (int k = 0; k < 5; ++k) {
      float2 a = p0[k], z = pl[k];
      float dx = z.x - a.x, dy = z.y - a.y;
      t = fmaf(dx, dx, fmaf(dy, dy, t));
    }
    total_disp = (t > 0.f) ? fsq(fmaxf(t, 1e-30f)) : 0.f;
  }

  // ---- load rows j=16q+s and j+1 ----
  float c[3][10], cn[3][10];
#pragma unroll
  for (int q = 0; q < 3; ++q) {
    const float2* p = reinterpret_cast<const float2*>(cp + (q * 16 + s) * 10);
#pragma unroll
    for (int k = 0; k < 5; ++k) { float2 v = p[k]; c[q][2*k] = v.x; c[q][2*k+1] = v.y; }
  }
#pragma unroll
  for (int q = 0; q < 3; ++q) {
    const int row = q * 16 + s + 1;
    if (row < 48) {
      const float2* p = reinterpret_cast<const float2*>(cp + row * 10);
#pragma unroll
      for (int k = 0; k < 5; ++k) { float2 v = p[k]; cn[q][2*k] = v.x; cn[q][2*k+1] = v.y; }
    } else {
#pragma unroll
      for (int k = 0; k < 10; ++k) cn[q][k] = 0.f;
    }
  }

  // ---- coord stats over rows < n ----
  float csl = 0.f, cs2l = 0.f;
#pragma unroll
  for (int q = 0; q < 3; ++q) {
    float t1 = 0.f, t2 = 0.f;
#pragma unroll
    for (int k = 0; k < 10; ++k) { t1 += c[q][k]; t2 = fmaf(c[q][k], c[q][k], t2); }
    const bool act = (q * 16 + s) < n;
    csl  += act ? t1 : 0.f;
    cs2l += act ? t2 : 0.f;
  }

  // ---- deltas + per-delta stats ----
  float d[3][10], inv[3];
  float path_l=0.f, dm2_l=0.f, maxdm_l=0.f, sf_l=0.f, ss_l=0.f, uu_l=0.f;
  float uk[10];
#pragma unroll
  for (int k = 0; k < 10; ++k) uk[k] = 0.f;
#pragma unroll
  for (int q = 0; q < 3; ++q) {
    const int j = q * 16 + s;
    float ds_ = 0.f;
#pragma unroll
    for (int k = 0; k < 10; ++k) { float dd = cn[q][k] - c[q][k]; d[q][k] = dd; ds_ = fmaf(dd, dd, ds_); }
    const float sn = (ds_ > 0.f) ? fsq(fmaxf(ds_, 1e-30f)) : 0.f;   // safe_norm
    inv[q] = frcp(fmaxf(sn, 1e-8f));                                // 1/na
    const bool jm = j < m;
    const float dm = jm ? sn : 0.f;
    path_l += dm;
    dm2_l  += jm ? ds_ : 0.f;
    maxdm_l = fmaxf(maxdm_l, dm);
    sf_l += (j <= half) ? dm : 0.f;
    ss_l += (j >= half) ? dm : 0.f;
    const float invm = jm ? inv[q] : 0.f;
#pragma unroll
    for (int k = 0; k < 10; ++k) uk[k] = fmaf(d[q][k], invm, uk[k]);
    uu_l = fmaf(ds_ * invm, invm, uu_l);
  }

  // ---- neighbor inv via ds_bpermute rotate-within-row ----
  const int rotb = (((lane & 48) | ((lane + 1) & 15)) << 2);
  const float rinv0 = __int_as_float(__builtin_amdgcn_ds_bpermute(rotb, __float_as_int(inv[0])));
  const float rinv1 = __int_as_float(__builtin_amdgcn_ds_bpermute(rotb, __float_as_int(inv[1])));
  const float rinv2 = __int_as_float(__builtin_amdgcn_ds_bpermute(rotb, __float_as_int(inv[2])));
  float invn[3];
  invn[0] = (s < 15) ? rinv0 : rinv1;
  invn[1] = (s < 15) ? rinv1 : rinv2;
  invn[2] = (s < 15) ? rinv2 : 0.f;

  // ---- cos / curvature (d_{j+1} from fresh row j+2 loads) ----
  float cos_l=0.f, cos2_l=0.f, ng_l=0.f, maxc_l=-INFINITY, minc_l=INFINITY;
  float curv0 = 0.f;
#pragma unroll
  for (int q = 0; q < 3; ++q) {
    const int j = q * 16 + s;
    float dn[10];
    if (j + 2 < 48) {
      const float2* p = reinterpret_cast<const float2*>(cp + (j + 2) * 10);
#pragma unroll
      for (int k = 0; k < 5; ++k) { float2 v = p[k]; dn[2*k] = v.x - cn[q][2*k]; dn[2*k+1] = v.y - cn[q][2*k+1]; }
    } else {
#pragma unroll
      for (int k = 0; k < 10; ++k) dn[k] = 0.f;
    }
    float dot = 0.f;
#pragma unroll
    for (int k = 0; k < 10; ++k) dot = fmaf(d[q][k], dn[k], dot);
    const float cosv = dot * inv[q] * invn[q];
    const bool ca = j < (n - 2);
    const float cm = ca ? cosv : 0.f;
    cos_l += cm;
    cos2_l = fmaf(cm, cm, cos2_l);
    maxc_l = fmaxf(maxc_l, ca ? cosv : -INFINITY);
    minc_l = fminf(minc_l, ca ? cosv :  INFINITY);
    ng_l += (cm < 0.f) ? 1.f : 0.f;
    if (q == 0) curv0 = ca ? (1.f - cosv) : 0.f;
  }

  // ---- row reductions (slot-15 valid only; no broadcast) ----
  const float path_len = rsum16s(path_l);
  const float sum_dm2  = rsum16s(dm2_l);
  const float max_dm   = rmax16s(maxdm_l);
  const float sum_f    = rsum16s(sf_l);
  const float sum_s    = rsum16s(ss_l);
  const float sum_cos  = rsum16s(cos_l);
  const float sum_cos2 = rsum16s(cos2_l);
  const float sum_ng   = rsum16s(ng_l);
  const float max_cos  = rmax16s(maxc_l);
  const float min_cos  = rmin16s(minc_l);
  const float sum_c    = rsum16s(csl);
  const float sum_c2   = rsum16s(cs2l);
  float Usq = 0.f;
#pragma unroll
  for (int k = 0; k < 10; ++k) { float Uk = rsum16s(uk[k]); Usq = fmaf(Uk, Uk, Usq); }
  const float sum_uu = rsum16s(uu_l);

  // ---- write the 60-feature vector to LDS (distributed writers) ----
  float* fb = lds + WOFF + T * FSTR;
  if (s < 3) {
#pragma unroll
    for (int k = 0; k < 10; ++k) fb[21 + s * 10 + k] = d[0][k];   // padded_deltas
  }
  if (s < 9) fb[51 + s] = curv0;                                   // padded_curvs
  if (s == 15) {
    const float EPSf = 1e-9f;
    const float nf = (float)n, mf = (float)m, ncf = (float)(n - 2);
    const float rncf = frcp(ncf);
    const float disp_ratio = total_disp * frcp(path_len + EPSf);
    const float sum_cv  = ncf - sum_cos;
    const float mean_cv = sum_cv * rncf;
    const float sum_cv2 = fmaf(-2.f, sum_cos, ncf) + sum_cos2;
    const float cv_var  = (sum_cv2 - ncf * mean_cv * mean_cv) * frcp(fmaxf(ncf - 1.f, 1.f));
    const float std_cv  = fsq(fmaxf(cv_var, 1e-30f));
    const float fh = sum_f * frcp((float)(half + 1));
    const float sh = sum_s * frcp((float)(m - half));
    const float conv = (fh - sh) * frcp(fh + EPSf);
    const float npairs = mf * (mf - 1.f) * 0.5f;
    const float par = (Usq - sum_uu) * 0.5f * frcp(npairs);
    const float mean_dm = path_len * frcp(mf);
    const float dm_var = (sum_dm2 - mf * mean_dm * mean_dm) * frcp(mf - 1.f);
    const float std_dm = fsq(fmaxf(dm_var, 1e-30f));
    const float jump = (mean_dm > EPSf) ? max_dm * frcp(mean_dm) : 1.f;
    const float cnt = nf * 10.f;
    const float mean_co = sum_c * frcp(cnt);
    const float co_var = (sum_c2 - cnt * mean_co * mean_co) * frcp(cnt - 1.f);
    const float std_co = fsq(fmaxf(co_var, 1e-30f));
    fb[0]  = total_disp;
    fb[1]  = path_len;
    fb[2]  = disp_ratio;
    fb[3]  = nf * 0.1f;
    fb[4]  = mean_cv;
    fb[5]  = 1.f - min_cos;           // max_curv
    fb[6]  = std_cv;
    fb[7]  = max_cos - min_cos;       // curv_range
    fb[8]  = sum_cos * rncf;          // mean_cos
    fb[9]  = min_cos;
    fb[10] = sum_ng * rncf;           // dir_changes
    fb[11] = disp_ratio;              // linearity
    fb[12] = 1.f - disp_ratio;        // loop_score
    fb[13] = conv;
    fb[14] = par;
    fb[15] = jump;
    fb[16] = -conv;                   // cascade
    fb[17] = mean_dm;
    fb[18] = std_dm;
    fb[19] = mean_co;
    fb[20] = std_co;
  }
  __builtin_amdgcn_wave_barrier();   // same-wave LDS RAW: DS is in-order; fence compiler only

  // ---- h_j = feat @ W + b for j = s, 16+s, 32+s (feats broadcast from LDS) ----
  float h0 = bias[s], h1 = bias[16 + s], h2 = bias[32 + s];
  const float4* fbv = reinterpret_cast<const float4*>(fb);
  const float4* w0  = reinterpret_cast<const float4*>(lds + (0 * 16 + s) * 60);
  const float4* w1  = reinterpret_cast<const float4*>(lds + (1 * 16 + s) * 60);
  const float4* w2  = reinterpret_cast<const float4*>(lds + (2 * 16 + s) * 60);
#pragma unroll
  for (int t = 0; t < 15; ++t) {
    float4 fv = fbv[t];
    float4 a = w0[t], bq = w1[t], cq = w2[t];
    h0 = fmaf(fv.x, a.x, h0);  h0 = fmaf(fv.y, a.y, h0);
    h0 = fmaf(fv.z, a.z, h0);  h0 = fmaf(fv.w, a.w, h0);
    h1 = fmaf(fv.x, bq.x, h1); h1 = fmaf(fv.y, bq.y, h1);
    h1 = fmaf(fv.z, bq.z, h1); h1 = fmaf(fv.w, bq.w, h1);
    h2 = fmaf(fv.x, cq.x, h2); h2 = fmaf(fv.y, cq.y, h2);
    h2 = fmaf(fv.z, cq.z, h2); h2 = fmaf(fv.w, cq.w, h2);
  }

  // ---- LayerNorm over the 48 outputs (row-broadcast sums) ----
  const float s1 = rsum16b(h0 + h1 + h2);
  const float s2 = rsum16b(fmaf(h0, h0, fmaf(h1, h1, h2 * h2)));
  const float mu  = s1 * (1.f / 48.f);
  const float var = fmaf(-mu, mu, s2 * (1.f / 48.f));
  const float rstd = __builtin_amdgcn_rsqf(var + 1e-5f);

  if (bvalid) {
    float hq[3] = {h0, h1, h2};
#pragma unroll
    for (int q = 0; q < 3; ++q) {
      const int j = q * 16 + s;
      float x = (hq[q] - mu) * rstd * lnw[j] + lnb[j];
      float x2 = x * x;
      float u  = 0.7978845608f * x * fmaf(0.044715f, x2, 1.f);
      float e  = __builtin_amdgcn_exp2f(u * 2.885390082f);   // e^{2u}
      float th = fmaf(-2.f, frcp(1.f + e), 1.f);
      out[(size_t)b * 48 + j] = 0.5f * x * (1.f + th);
    }
  }
}

extern "C" void kernel_launch(void* const* d_in, const int* in_sizes, int n_in,
                              void* d_out, int out_size, void* d_ws, size_t ws_size,
                              hipStream_t stream)
{
  const float* coords = (const float*)d_in[0];
  const int*   lengths= (const int*)d_in[1];
  const float* W      = (const float*)d_in[2];
  const float* bias   = (const float*)d_in[3];
  const float* lnw    = (const float*)d_in[4];
  const float* lnb    = (const float*)d_in[5];
  float* out = (float*)d_out;

  const int B = in_sizes[1];
  const int blocks = (B + 15) / 16;   // 16 trajectories per 256-thread block

  if (ws_size >= (size_t)(60 * 48 * sizeof(float))) {
    float* Wt = (float*)d_ws;
    transpose_w<<<12, 256, 0, stream>>>(W, Wt);
    traj_kernel<true><<<blocks, 256, 0, stream>>>(coords, lengths, Wt, bias, lnw, lnb, out, B);
  } else {
    traj_kernel<false><<<blocks, 256, 0, stream>>>(coords, lengths, W, bias, lnw, lnb, out, B);
  }
}

// Round 8
// 131.564 us; speedup vs baseline: 1.0611x; 1.0611x over previous
//
#include <hip/hip_runtime.h>
#include <math.h>

static __device__ __forceinline__ float frcp(float x){ return __builtin_amdgcn_rcpf(x); }
static __device__ __forceinline__ float fsq (float x){ return __builtin_amdgcn_sqrtf(x); }

// ---- DPP partial reductions within rows of 16 ----
template<int CTRL>
static __device__ __forceinline__ float dppadd(float x){
  int t = __builtin_amdgcn_update_dpp(0, __float_as_int(x), CTRL, 0xf, 0xf, true);
  return x + __int_as_float(t);
}
template<int CTRL>
static __device__ __forceinline__ float dppmax(float x){
  int t = __builtin_amdgcn_update_dpp(__float_as_int(x), __float_as_int(x), CTRL, 0xf, 0xf, false);
  return fmaxf(x, __int_as_float(t));
}
template<int CTRL>
static __device__ __forceinline__ float dppmin(float x){
  int t = __builtin_amdgcn_update_dpp(__float_as_int(x), __float_as_int(x), CTRL, 0xf, 0xf, false);
  return fminf(x, __int_as_float(t));
}
template<int OFF>
static __device__ __forceinline__ float swz(float x){
  return __int_as_float(__builtin_amdgcn_ds_swizzle(__float_as_int(x), OFF));
}
// reduce over the 32-lane half, result broadcast to all 32 lanes
// after 4 row_shr steps lane15 holds sum(0..15), lane31 holds sum(16..31);
// swizzle or=0xF (0x1E0) fetches lane15, or=0x1F (0x3E0) fetches lane31.
static __device__ __forceinline__ float rsum32(float x){
  x = dppadd<0x111>(x); x = dppadd<0x112>(x);
  x = dppadd<0x114>(x); x = dppadd<0x118>(x);
  return swz<0x1E0>(x) + swz<0x3E0>(x);
}
static __device__ __forceinline__ float rmax32(float x){
  x = dppmax<0x111>(x); x = dppmax<0x112>(x);
  x = dppmax<0x114>(x); x = dppmax<0x118>(x);
  return fmaxf(swz<0x1E0>(x), swz<0x3E0>(x));
}
static __device__ __forceinline__ float rmin32(float x){
  x = dppmin<0x111>(x); x = dppmin<0x112>(x);
  x = dppmin<0x114>(x); x = dppmin<0x118>(x);
  return fminf(swz<0x1E0>(x), swz<0x3E0>(x));
}
// broadcast slot P of each 32-lane half (and=0, or=P)
#define BC32(P, x) swz<((P) << 5)>(x)

__global__ void transpose_w(const float* __restrict__ W, float* __restrict__ Wt){
  int idx = blockIdx.x * 256 + threadIdx.x;
  if (idx < 60 * 48) { int f = idx / 48, j = idx - f * 48; Wt[j * 60 + f] = W[idx]; }
}

template<bool USEWT>
__global__ __launch_bounds__(256)
void traj_kernel(const float* __restrict__ coords,
                 const int* __restrict__ lengths,
                 const float* __restrict__ Wsrc,   // Wt [48][60] if USEWT else W [60][48]
                 const float* __restrict__ bias,
                 const float* __restrict__ lnw,
                 const float* __restrict__ lnb,
                 float* __restrict__ out, int B)
{
  const int tid  = threadIdx.x;
  const int lane = tid & 63;
  const int w    = lane & 31;                        // slot within 32-lane group
  const int T    = ((tid >> 6) << 1) | (lane >> 5);  // trajectory in block, 0..7
  const int grp  = blockIdx.x * 8 + T;
  const bool bvalid = (grp < B);
  const int b = bvalid ? grp : (B - 1);

  const int n = lengths[b];            // group-uniform, 4..48
  const int m = n - 1;
  const int half = m >> 1;             // half <= 23 < 32
  const float* cp = coords + (size_t)b * 480;

  // ---- load rows: chunk0 = rows w, w+1 (always valid); chunk1 = rows 32+w, 33+w (w<16) ----
  float c0[10], cn0[10], c1[10], cn1[10];
  {
    const float2* p = reinterpret_cast<const float2*>(cp + w * 10);
#pragma unroll
    for (int k = 0; k < 5; ++k){ float2 v = p[k]; c0[2*k]=v.x; c0[2*k+1]=v.y; }
    p = reinterpret_cast<const float2*>(cp + (w + 1) * 10);
#pragma unroll
    for (int k = 0; k < 5; ++k){ float2 v = p[k]; cn0[2*k]=v.x; cn0[2*k+1]=v.y; }
  }
  if (w < 16) {
    const float2* p = reinterpret_cast<const float2*>(cp + (32 + w) * 10);
#pragma unroll
    for (int k = 0; k < 5; ++k){ float2 v = p[k]; c1[2*k]=v.x; c1[2*k+1]=v.y; }
    if (w < 15) {
      p = reinterpret_cast<const float2*>(cp + (33 + w) * 10);
#pragma unroll
      for (int k = 0; k < 5; ++k){ float2 v = p[k]; cn1[2*k]=v.x; cn1[2*k+1]=v.y; }
    } else {
#pragma unroll
      for (int k = 0; k < 10; ++k) cn1[k] = 0.f;     // row 48 doesn't exist; delta 47 masked
    }
  } else {
#pragma unroll
    for (int k = 0; k < 10; ++k) { c1[k] = 0.f; cn1[k] = 0.f; }
  }

  // ---- coord stats over rows < n ----
  float csl = 0.f, cs2l = 0.f;
  {
    float t1 = 0.f, t2 = 0.f;
#pragma unroll
    for (int k = 0; k < 10; ++k) { t1 += c0[k]; t2 = fmaf(c0[k], c0[k], t2); }
    const bool a0 = w < n;
    csl  += a0 ? t1 : 0.f;  cs2l += a0 ? t2 : 0.f;
    t1 = 0.f; t2 = 0.f;
#pragma unroll
    for (int k = 0; k < 10; ++k) { t1 += c1[k]; t2 = fmaf(c1[k], c1[k], t2); }
    const bool a1 = (w < 16) && (32 + w < n);
    csl  += a1 ? t1 : 0.f;  cs2l += a1 ? t2 : 0.f;
  }

  // ---- total displacement ||row_{n-1} - row_0|| ----
  float cc0k[10];
#pragma unroll
  for (int k = 0; k < 10; ++k) cc0k[k] = BC32(0, c0[k]);
  const int ssl = (n - 1) & 31, qs = (n - 1) >> 5;   // qs==1 => ssl<16
  float tq0 = 0.f, tq1 = 0.f;
#pragma unroll
  for (int k = 0; k < 10; ++k) {
    float t = c0[k] - cc0k[k]; tq0 = fmaf(t, t, tq0);
    t = c1[k] - cc0k[k];       tq1 = fmaf(t, t, tq1);
  }
  const float tql = (w == ssl) ? (qs ? tq1 : tq0) : 0.f;
  const float tdq = rsum32(tql);
  const float total_disp = (tdq > 0.f) ? fsq(fmaxf(tdq, 1e-30f)) : 0.f;

  // ---- deltas ----
  float d0[10], d1[10];
  float ds0 = 0.f, ds1 = 0.f;
#pragma unroll
  for (int k = 0; k < 10; ++k) { float t = cn0[k] - c0[k]; d0[k] = t; ds0 = fmaf(t, t, ds0); }
#pragma unroll
  for (int k = 0; k < 10; ++k) { float t = cn1[k] - c1[k]; d1[k] = t; ds1 = fmaf(t, t, ds1); }
  const float sn0 = (ds0 > 0.f) ? fsq(fmaxf(ds0, 1e-30f)) : 0.f;
  const float sn1 = (ds1 > 0.f) ? fsq(fmaxf(ds1, 1e-30f)) : 0.f;
  const float inv0 = frcp(fmaxf(sn0, 1e-8f));
  const float inv1 = frcp(fmaxf(sn1, 1e-8f));
  const bool dact0 = (w < m);
  const bool dact1 = (w < 16) && (32 + w < m);
  const float dm0 = dact0 ? sn0 : 0.f;
  const float dm1 = dact1 ? sn1 : 0.f;
  const float path_l  = dm0 + dm1;
  const float dm2_l   = (dact0 ? ds0 : 0.f) + (dact1 ? ds1 : 0.f);
  const float maxdm_l = fmaxf(dm0, dm1);
  const float sf_l    = (w <= half) ? dm0 : 0.f;            // 32+w<=half impossible (half<=23)
  const float ss_l    = ((w >= half) ? dm0 : 0.f) + dm1;    // 32+w>=half always
  const float i0m = dact0 ? inv0 : 0.f, i1m = dact1 ? inv1 : 0.f;
  float uk[10];
#pragma unroll
  for (int k = 0; k < 10; ++k) uk[k] = fmaf(d0[k], i0m, d1[k] * i1m);
  const float uu_l = fmaf(ds0 * i0m, i0m, ds1 * i1m * i1m);

  // ---- neighbor inv via ds_bpermute within the 32-group ----
  const int rotb = ((lane & 0x20) | ((w + 1) & 31)) << 2;
  const float rinv0 = __int_as_float(__builtin_amdgcn_ds_bpermute(rotb, __float_as_int(inv0)));
  const float rinv1 = __int_as_float(__builtin_amdgcn_ds_bpermute(rotb, __float_as_int(inv1)));
  const float invn0 = (w < 31) ? rinv0 : rinv1;   // w=31: delta 32 = lane0's chunk1
  const float invn1 = rinv1;                      // valid for w<15; masked otherwise

  // ---- cos / curvature ----
  float cos_l, cos2_l, ng_l, maxc_l, minc_l, curv0;
  {
    // chunk0: d_{w+1} from row w+2 (w+2 <= 33 always valid)
    float dot0 = 0.f;
    {
      const float2* p = reinterpret_cast<const float2*>(cp + (w + 2) * 10);
#pragma unroll
      for (int k = 0; k < 5; ++k) {
        float2 v = p[k];
        dot0 = fmaf(d0[2*k],   v.x - cn0[2*k],   dot0);
        dot0 = fmaf(d0[2*k+1], v.y - cn0[2*k+1], dot0);
      }
    }
    const float cosv0 = dot0 * inv0 * invn0;
    const bool ca0 = w < (n - 2);
    // chunk1: d_{33+w} from row 34+w (valid w<14; cos j=32+w needs j<n-2<=46 -> w<=13)
    float dot1 = 0.f;
    if (w < 14) {
      const float2* p = reinterpret_cast<const float2*>(cp + (34 + w) * 10);
#pragma unroll
      for (int k = 0; k < 5; ++k) {
        float2 v = p[k];
        dot1 = fmaf(d1[2*k],   v.x - cn1[2*k],   dot1);
        dot1 = fmaf(d1[2*k+1], v.y - cn1[2*k+1], dot1);
      }
    }
    const float cosv1 = dot1 * inv1 * invn1;
    const bool ca1 = (w < 16) && (32 + w < (n - 2));
    const float cm0 = ca0 ? cosv0 : 0.f;
    const float cm1 = ca1 ? cosv1 : 0.f;
    cos_l  = cm0 + cm1;
    cos2_l = fmaf(cm0, cm0, cm1 * cm1);
    maxc_l = fmaxf(ca0 ? cosv0 : -INFINITY, ca1 ? cosv1 : -INFINITY);
    minc_l = fminf(ca0 ? cosv0 :  INFINITY, ca1 ? cosv1 :  INFINITY);
    ng_l   = ((cm0 < 0.f) ? 1.f : 0.f) + ((cm1 < 0.f) ? 1.f : 0.f);
    curv0  = ca0 ? (1.f - cosv0) : 0.f;           // rows 0..8 live in chunk0 lanes 0..8
  }

  // ---- group reductions (broadcast results) ----
  const float path_len = rsum32(path_l);
  const float sum_dm2  = rsum32(dm2_l);
  const float max_dm   = rmax32(maxdm_l);
  const float sum_f    = rsum32(sf_l);
  const float sum_s    = rsum32(ss_l);
  const float sum_cos  = rsum32(cos_l);
  const float sum_cos2 = rsum32(cos2_l);
  const float sum_ng   = rsum32(ng_l);
  const float max_cos  = rmax32(maxc_l);
  const float min_cos  = rmin32(minc_l);
  const float sum_c    = rsum32(csl);
  const float sum_c2   = rsum32(cs2l);
  float Usq = 0.f;
#pragma unroll
  for (int k = 0; k < 10; ++k) { float Uk = rsum32(uk[k]); Usq = fmaf(Uk, Uk, Usq); }
  const float sum_uu = rsum32(uu_l);

  // ---- scalar features (group-uniform) ----
  const float EPSf = 1e-9f;
  const float nf = (float)n, mf = (float)m, ncf = (float)(n - 2);
  const float rncf = frcp(ncf);
  const float disp_ratio = total_disp * frcp(path_len + EPSf);
  const float sum_cv  = ncf - sum_cos;
  const float mean_cv = sum_cv * rncf;
  const float sum_cv2 = fmaf(-2.f, sum_cos, ncf) + sum_cos2;
  const float cv_var  = (sum_cv2 - ncf * mean_cv * mean_cv) * frcp(fmaxf(ncf - 1.f, 1.f));
  const float std_cv  = fsq(fmaxf(cv_var, 1e-30f));
  const float fh = sum_f * frcp((float)(half + 1));
  const float sh = sum_s * frcp((float)(m - half));
  const float conv = (fh - sh) * frcp(fh + EPSf);
  const float npairs = mf * (mf - 1.f) * 0.5f;
  const float par = (Usq - sum_uu) * 0.5f * frcp(npairs);
  const float mean_dm = path_len * frcp(mf);
  const float dm_var = (sum_dm2 - mf * mean_dm * mean_dm) * frcp(mf - 1.f);
  const float std_dm = fsq(fmaxf(dm_var, 1e-30f));
  const float jump = (mean_dm > EPSf) ? max_dm * frcp(mean_dm) : 1.f;
  const float cnt = nf * 10.f;
  const float mean_co = sum_c * frcp(cnt);
  const float co_var = (sum_c2 - cnt * mean_co * mean_co) * frcp(cnt - 1.f);
  const float std_co = fsq(fmaxf(co_var, 1e-30f));

  // ---- 60 features (group-uniform in VGPRs) ----
  float feat[60];
  feat[0]  = total_disp;
  feat[1]  = path_len;
  feat[2]  = disp_ratio;
  feat[3]  = nf * 0.1f;
  feat[4]  = mean_cv;
  feat[5]  = 1.f - min_cos;           // max_curv
  feat[6]  = std_cv;
  feat[7]  = max_cos - min_cos;       // curv_range
  feat[8]  = sum_cos * rncf;          // mean_cos
  feat[9]  = min_cos;
  feat[10] = sum_ng * rncf;           // dir_changes
  feat[11] = disp_ratio;              // linearity
  feat[12] = 1.f - disp_ratio;        // loop_score
  feat[13] = conv;
  feat[14] = par;
  feat[15] = jump;
  feat[16] = -conv;                   // cascade
  feat[17] = mean_dm;
  feat[18] = std_dm;
  feat[19] = mean_co;
  feat[20] = std_co;
#pragma unroll
  for (int k = 0; k < 10; ++k) feat[21 + k] = BC32(0, d0[k]);
#pragma unroll
  for (int k = 0; k < 10; ++k) feat[31 + k] = BC32(1, d0[k]);
#pragma unroll
  for (int k = 0; k < 10; ++k) feat[41 + k] = BC32(2, d0[k]);
  feat[51] = BC32(0, curv0); feat[52] = BC32(1, curv0); feat[53] = BC32(2, curv0);
  feat[54] = BC32(3, curv0); feat[55] = BC32(4, curv0); feat[56] = BC32(5, curv0);
  feat[57] = BC32(6, curv0); feat[58] = BC32(7, curv0); feat[59] = BC32(8, curv0);

  // ---- h_j = feat @ W + b for j = w (all lanes) and j = 32+w (w<16) ----
  const int j1 = 32 + (w & 15);       // clamped so loads stay in-bounds; unused for w>=16
  float h0 = bias[w], h1 = bias[j1];
  if (USEWT) {
    const float4* w0 = reinterpret_cast<const float4*>(Wsrc + w  * 60);
    const float4* w1 = reinterpret_cast<const float4*>(Wsrc + j1 * 60);
#pragma unroll
    for (int t = 0; t < 15; ++t) {
      float4 a = w0[t], bq = w1[t];
      h0 = fmaf(feat[4*t+0], a.x, h0);  h0 = fmaf(feat[4*t+1], a.y, h0);
      h0 = fmaf(feat[4*t+2], a.z, h0);  h0 = fmaf(feat[4*t+3], a.w, h0);
      h1 = fmaf(feat[4*t+0], bq.x, h1); h1 = fmaf(feat[4*t+1], bq.y, h1);
      h1 = fmaf(feat[4*t+2], bq.z, h1); h1 = fmaf(feat[4*t+3], bq.w, h1);
    }
  } else {
#pragma unroll
    for (int f = 0; f < 60; ++f) {
      h0 = fmaf(feat[f], Wsrc[f * 48 + w],  h0);
      h1 = fmaf(feat[f], Wsrc[f * 48 + j1], h1);
    }
  }

  // ---- LayerNorm over the 48 outputs ----
  const float h1m = (w < 16) ? h1 : 0.f;
  const float s1 = rsum32(h0 + h1m);
  const float s2 = rsum32(fmaf(h0, h0, h1m * h1m));
  const float mu  = s1 * (1.f / 48.f);
  const float var = fmaf(-mu, mu, s2 * (1.f / 48.f));
  const float rstd = __builtin_amdgcn_rsqf(var + 1e-5f);

  if (bvalid) {
    {
      float x = (h0 - mu) * rstd * lnw[w] + lnb[w];
      float x2 = x * x;
      float u  = 0.7978845608f * x * fmaf(0.044715f, x2, 1.f);
      float e  = __builtin_amdgcn_exp2f(u * 2.885390082f);   // e^{2u}
      float th = fmaf(-2.f, frcp(1.f + e), 1.f);
      out[(size_t)b * 48 + w] = 0.5f * x * (1.f + th);
    }
    if (w < 16) {
      float x = (h1 - mu) * rstd * lnw[j1] + lnb[j1];
      float x2 = x * x;
      float u  = 0.7978845608f * x * fmaf(0.044715f, x2, 1.f);
      float e  = __builtin_amdgcn_exp2f(u * 2.885390082f);
      float th = fmaf(-2.f, frcp(1.f + e), 1.f);
      out[(size_t)b * 48 + j1] = 0.5f * x * (1.f + th);
    }
  }
}

extern "C" void kernel_launch(void* const* d_in, const int* in_sizes, int n_in,
                              void* d_out, int out_size, void* d_ws, size_t ws_size,
                              hipStream_t stream)
{
  const float* coords = (const float*)d_in[0];
  const int*   lengths= (const int*)d_in[1];
  const float* W      = (const float*)d_in[2];
  const float* bias   = (const float*)d_in[3];
  const float* lnw    = (const float*)d_in[4];
  const float* lnb    = (const float*)d_in[5];
  float* out = (float*)d_out;

  const int B = in_sizes[1];
  const int blocks = (B + 7) / 8;     // 8 trajectories per 256-thread block (2 per wave)

  if (ws_size >= (size_t)(60 * 48 * sizeof(float))) {
    float* Wt = (float*)d_ws;
    transpose_w<<<12, 256, 0, stream>>>(W, Wt);
    traj_kernel<true><<<blocks, 256, 0, stream>>>(coords, lengths, Wt, bias, lnw, lnb, out, B);
  } else {
    traj_kernel<false><<<blocks, 256, 0, stream>>>(coords, lengths, W, bias, lnw, lnb, out, B);
  }
}